// Round 13
// baseline (555.417 us; speedup 1.0000x reference)
//
#include <hip/hip_runtime.h>

#define NN 50000
#define NE 500000
#define HD 128
#define HD2 256
#define NL 4
#define NG 1000

constexpr float MSG_EPS = 1e-7f;
constexpr float LNEPS   = 1e-5f;
constexpr float LOG2E   = 1.4426950408889634f;

typedef float  f32x4  __attribute__((ext_vector_type(4)));
typedef float  f32x2  __attribute__((ext_vector_type(2)));
typedef __bf16 bf16x8 __attribute__((ext_vector_type(8)));

__device__ __forceinline__ unsigned short f2b(float f) {
    unsigned int u = __float_as_uint(f);
    unsigned int r = u + 0x7FFFu + ((u >> 16) & 1u);
    return (unsigned short)(r >> 16);
}
__device__ __forceinline__ float b2f(unsigned short h) {
    return __uint_as_float(((unsigned int)h) << 16);
}
__device__ __forceinline__ unsigned int pack2(float a, float b) {
    return (unsigned int)f2b(a) | ((unsigned int)f2b(b) << 16);
}

// ---------------- merged setup: weight prep + node encoder + dst histogram ----------
#define PREP_BLKS 512
#define ENC_BLKS 25000  // 2 nodes per 256-thr block
#define HIST_BLKS ((NE + 255) / 256)

__global__ void k_setup(const float* __restrict__ x, const float* __restrict__ encW,
                        const float* __restrict__ encB, unsigned short* __restrict__ zb,
                        const float* __restrict__ W1, const float* __restrict__ W2,
                        unsigned short* __restrict__ W1T, unsigned short* __restrict__ W2T,
                        const int* __restrict__ dst, int* __restrict__ counts) {
    int bid = blockIdx.x, tid = threadIdx.x;
    if (bid < PREP_BLKS) {
        int idx = bid * 256 + tid;  // 131072 total
        {
            int k = idx & 127, n = (idx >> 7) & 255, l = idx >> 15;
            W1T[idx] = f2b(W1[(l * 128 + k) * 256 + n]);
        }
        {
            int k = idx & 255, n = (idx >> 8) & 127, l = idx >> 15;
            W2T[idx] = f2b(W2[(l * 256 + k) * 128 + n]);
        }
    } else if (bid < PREP_BLKS + ENC_BLKS) {
        int n = (bid - PREP_BLKS) * 2 + (tid >> 7);
        int c = tid & 127;
        float xr[9];
#pragma unroll
        for (int k = 0; k < 9; k++) xr[k] = x[n * 9 + k];
        float acc = encB[c];
#pragma unroll
        for (int k = 0; k < 9; k++) acc = fmaf(xr[k], encW[k * HD + c], acc);
        zb[(size_t)n * HD + c] = f2b(acc);
    } else {
        int e = (bid - PREP_BLKS - ENC_BLKS) * 256 + tid;
        if (e < NE) atomicAdd(&counts[dst[e]], 1);
    }
}

// ---------------- CSR scan ----------------
#define SCAN_B 512
#define NSB ((NN + SCAN_B - 1) / SCAN_B)  // 98

__global__ void k_scan1(const int* __restrict__ counts, int* __restrict__ incl,
                        int* __restrict__ bsum) {
    __shared__ int s[SCAN_B];
    int i = blockIdx.x * SCAN_B + threadIdx.x;
    int v = (i < NN) ? counts[i] : 0;
    s[threadIdx.x] = v;
    __syncthreads();
    for (int off = 1; off < SCAN_B; off <<= 1) {
        int t = (threadIdx.x >= off) ? s[threadIdx.x - off] : 0;
        __syncthreads();
        s[threadIdx.x] += t;
        __syncthreads();
    }
    if (i < NN) incl[i] = s[threadIdx.x];
    if (threadIdx.x == SCAN_B - 1) bsum[blockIdx.x] = s[threadIdx.x];
}

__global__ void k_scan2(const int* __restrict__ bsum, int* __restrict__ boff, int nb) {
    __shared__ int s[128];
    int v = (threadIdx.x < nb) ? bsum[threadIdx.x] : 0;
    s[threadIdx.x] = v;
    __syncthreads();
    for (int off = 1; off < 128; off <<= 1) {
        int t = (threadIdx.x >= off) ? s[threadIdx.x - off] : 0;
        __syncthreads();
        s[threadIdx.x] += t;
        __syncthreads();
    }
    if (threadIdx.x < nb) boff[threadIdx.x] = s[threadIdx.x] - v;  // exclusive
}

// scan finalize + group-bounds binary search (merged)
__global__ void k_scan3g(const int* __restrict__ incl, const int* __restrict__ boff,
                         int* __restrict__ row_start, const int* __restrict__ batch,
                         int* __restrict__ gstart) {
    if (blockIdx.x < NSB) {
        int i = blockIdx.x * SCAN_B + threadIdx.x;
        if (i < NN) row_start[i + 1] = incl[i] + boff[blockIdx.x];
        if (i == 0) row_start[0] = 0;
    } else {
        int g = (blockIdx.x - NSB) * SCAN_B + threadIdx.x;
        if (g > NG) return;
        int lo = 0, hi = NN;
        while (lo < hi) {
            int mid = (lo + hi) >> 1;
            if (batch[mid] < g) lo = mid + 1;
            else hi = mid;
        }
        gstart[g] = lo;
    }
}

// pack {attr0, attr1, attr2, src} per CSR slot
__global__ void k_scatter(const int* __restrict__ src, const int* __restrict__ dst,
                          const float* __restrict__ eattr, const int* __restrict__ row_start,
                          int* __restrict__ cursor, float4* __restrict__ aperm) {
    int e = blockIdx.x * blockDim.x + threadIdx.x;
    if (e >= NE) return;
    int d = dst[e];
    int p = row_start[d] + atomicAdd(&cursor[d], 1);
    float4 v;
    v.x = eattr[e * 3 + 0];
    v.y = eattr[e * 3 + 1];
    v.z = eattr[e * 3 + 2];
    v.w = __int_as_float(src[e]);
    aperm[p] = v;
}

// ---------------- per-edge softmax-agg accumulate (2 ch/lane, packed fp32) ----------
// eps folded to epilogue; exp via exp2 with pre-scaled t*log2(e).
__device__ __forceinline__ void edge_acc2(float4 a, unsigned int zz, f32x2 w0, f32x2 w1,
                                          f32x2 w2, f32x2 bb, float t2, f32x2& num,
                                          f32x2& wm) {
    f32x2 z;
    z.x = __uint_as_float(zz << 16);
    z.y = __uint_as_float(zz & 0xFFFF0000u);
    f32x2 m = z + bb + a.x * w0 + a.y * w1 + a.z * w2;  // v_pk_fma chain
    m.x = fmaxf(m.x, 0.f);
    m.y = fmaxf(m.y, 0.f);
    f32x2 e;
    e.x = exp2f(t2 * m.x);
    e.y = exp2f(t2 * m.y);
    num += e;     // v_pk_add
    wm += m * e;  // v_pk_fma
}

// ---------------- softmax aggregation: one wave per node, 2 ch/lane, unroll-8 ------
// row bounds + gather base scalarized via readfirstlane -> uniform edge loop, SALU addr.
__global__ __launch_bounds__(256) void k_aggregate(const unsigned short* __restrict__ zbin,
                                                   const float4* __restrict__ aperm,
                                                   const int* __restrict__ row_start,
                                                   const float* __restrict__ We,
                                                   const float* __restrict__ be,
                                                   const float* __restrict__ t, int layer,
                                                   unsigned int* __restrict__ outb) {
    int w = threadIdx.x >> 6, lane = threadIdx.x & 63;
    int n = blockIdx.x * 4 + w;
    if (n >= NN) return;
    int c = lane * 2;
    f32x2 w0 = *(const f32x2*)&We[c];
    f32x2 w1 = *(const f32x2*)&We[HD + c];
    f32x2 w2 = *(const f32x2*)&We[2 * HD + c];
    f32x2 bb = *(const f32x2*)&be[c];
    float t2 = t[layer] * LOG2E;
    int s0 = __builtin_amdgcn_readfirstlane(row_start[n]);
    int s1 = __builtin_amdgcn_readfirstlane(row_start[n + 1]);
    f32x2 num = (f32x2){0.f, 0.f}, wm = (f32x2){0.f, 0.f};
    const unsigned int* z32 = (const unsigned int*)zbin;
    int p = s0;
    for (; p + 8 <= s1; p += 8) {
        float4 A[8];
#pragma unroll
        for (int j = 0; j < 8; j++) A[j] = aperm[p + j];
        unsigned int Z[8];
#pragma unroll
        for (int j = 0; j < 8; j++) {
            int sj = __builtin_amdgcn_readfirstlane(__float_as_int(A[j].w));
            Z[j] = z32[(size_t)sj * 64 + lane];
        }
#pragma unroll
        for (int j = 0; j < 8; j++) edge_acc2(A[j], Z[j], w0, w1, w2, bb, t2, num, wm);
    }
    for (; p + 4 <= s1; p += 4) {
        float4 A[4];
#pragma unroll
        for (int j = 0; j < 4; j++) A[j] = aperm[p + j];
        unsigned int Z[4];
#pragma unroll
        for (int j = 0; j < 4; j++) {
            int sj = __builtin_amdgcn_readfirstlane(__float_as_int(A[j].w));
            Z[j] = z32[(size_t)sj * 64 + lane];
        }
#pragma unroll
        for (int j = 0; j < 4; j++) edge_acc2(A[j], Z[j], w0, w1, w2, bb, t2, num, wm);
    }
    for (; p < s1; p++) {
        float4 a = aperm[p];
        int sj = __builtin_amdgcn_readfirstlane(__float_as_int(a.w));
        unsigned int zz = z32[(size_t)sj * 64 + lane];
        edge_acc2(a, zz, w0, w1, w2, bb, t2, num, wm);
    }
    unsigned int zn = z32[(size_t)n * 64 + lane];
    bool has = s1 > s0;
    float ox = (has ? (wm.x / num.x + MSG_EPS) : 0.f) + __uint_as_float(zn << 16);
    float oy = (has ? (wm.y / num.y + MSG_EPS) : 0.f) + __uint_as_float(zn & 0xFFFF0000u);
    outb[(size_t)n * 64 + lane] = pack2(ox, oy);
}

// ---------------- fused MFMA MLP + next-layer LN+relu, BM=16 ----------------
// hnew = (add? h : 0) + relu(LN(A@W1+b1))@W2+b2 ; h=bf16(hnew); zb=bf16(relu(LN_next(hnew)))
// BM=16 (grid 3125 EXACT, no bounds checks), 4 waves. Wave w owns cols w*64.. (GEMM1)
// and w*32.. (GEMM2) of all 16 rows. In-register LN1 stats (st1 exchange). 3 barriers.
// LDS 13.3 KB -> 8 blocks/CU (wave-capped).
#define BM 16
#define HS_LD 264  // bf16 row stride (256+8)
#define HT_LD 136  // bf16 row stride (128+8); as uint: 68

__global__ __launch_bounds__(256) void k_mlp(const unsigned short* __restrict__ outb,
                                             const unsigned short* __restrict__ W1T,
                                             const float* __restrict__ b1l,
                                             const float* __restrict__ lgl,
                                             const float* __restrict__ lbl,
                                             const unsigned short* __restrict__ W2T,
                                             const float* __restrict__ b2l,
                                             unsigned short* __restrict__ h,
                                             const float* __restrict__ gn,
                                             const float* __restrict__ bn,
                                             unsigned short* __restrict__ zb,
                                             int add_residual) {
    __shared__ __align__(16) unsigned short Hs[BM * HS_LD];  // 8448 B
    __shared__ __align__(16) unsigned short Ht[BM * HT_LD];  // 4352 B
    __shared__ __align__(16) float2 st1[16][4];              // 512 B

    int nb = blockIdx.x * BM;
    int tid = threadIdx.x;
    int w = tid >> 6, lane = tid & 63, q = lane >> 4, i = lane & 15;

    // ---- GEMM1: 16x256, K=128; A from global bf16 outb, 1-step lookahead ----
    f32x4 acc[4];
#pragma unroll
    for (int ct = 0; ct < 4; ct++) acc[ct] = (f32x4){0.f, 0.f, 0.f, 0.f};

    bf16x8 acur, bcur[4];
    acur = *(const bf16x8*)&outb[(size_t)(nb + i) * HD + q * 8];
#pragma unroll
    for (int ct = 0; ct < 4; ct++)
        bcur[ct] = *(const bf16x8*)&W1T[(w * 64 + ct * 16 + i) * HD + q * 8];

#pragma unroll
    for (int ks = 0; ks < 4; ks++) {
        bf16x8 anxt, bnxt[4];
        if (ks < 3) {
            anxt = *(const bf16x8*)&outb[(size_t)(nb + i) * HD + (ks + 1) * 32 + q * 8];
#pragma unroll
            for (int ct = 0; ct < 4; ct++)
                bnxt[ct] =
                    *(const bf16x8*)&W1T[(w * 64 + ct * 16 + i) * HD + (ks + 1) * 32 + q * 8];
        }
#pragma unroll
        for (int ct = 0; ct < 4; ct++)
            acc[ct] = __builtin_amdgcn_mfma_f32_16x16x32_bf16(acur, bcur[ct], acc[ct], 0, 0, 0);
        if (ks < 3) {
            acur = anxt;
#pragma unroll
            for (int ct = 0; ct < 4; ct++) bcur[ct] = bnxt[ct];
        }
    }

    // ---- +b1 ----
#pragma unroll
    for (int ct = 0; ct < 4; ct++) {
        float bb = b1l[w * 64 + ct * 16 + i];
#pragma unroll
        for (int r = 0; r < 4; r++) acc[ct][r] += bb;
    }

    // ---- LN(256) stats in-register + cross-wave exchange ----
    {
        float sv[4], qv[4];
#pragma unroll
        for (int r = 0; r < 4; r++) {
            sv[r] = acc[0][r] + acc[1][r] + acc[2][r] + acc[3][r];
            float sq = 0.f;
#pragma unroll
            for (int ct = 0; ct < 4; ct++) sq = fmaf(acc[ct][r], acc[ct][r], sq);
            qv[r] = sq;
        }
#pragma unroll
        for (int m = 1; m <= 8; m <<= 1)
#pragma unroll
            for (int r = 0; r < 4; r++) {
                sv[r] += __shfl_xor(sv[r], m);
                qv[r] += __shfl_xor(qv[r], m);
            }
        if (i == 0) {
#pragma unroll
            for (int r = 0; r < 4; r++) st1[q * 4 + r][w] = make_float2(sv[r], qv[r]);
        }
    }
    __syncthreads();

    {
        float mu[4], inv[4];
#pragma unroll
        for (int r = 0; r < 4; r++) {
            const float4* sp = (const float4*)&st1[q * 4 + r][0];
            float4 a = sp[0], b = sp[1];
            float S = a.x + a.z + b.x + b.z;
            float Q = a.y + a.w + b.y + b.w;
            float m_ = S * (1.f / 256.f);
            float v_ = Q * (1.f / 256.f) - m_ * m_;
            mu[r] = m_;
            inv[r] = rsqrtf(v_ + LNEPS);
        }
#pragma unroll
        for (int ct = 0; ct < 4; ct++) {
            float g = lgl[w * 64 + ct * 16 + i];
            float c = lbl[w * 64 + ct * 16 + i];
#pragma unroll
            for (int r = 0; r < 4; r++) {
                float v = fmaxf(fmaf((acc[ct][r] - mu[r]) * inv[r], g, c), 0.f);
                Hs[(q * 4 + r) * HS_LD + w * 64 + ct * 16 + i] = f2b(v);
            }
        }
    }
    __syncthreads();

    // ---- GEMM2: 16x128, K=256; A from Hs, 1-step lookahead ----
    f32x4 acc2[2];
#pragma unroll
    for (int ct = 0; ct < 2; ct++) acc2[ct] = (f32x4){0.f, 0.f, 0.f, 0.f};

    bf16x8 hc, bc[2];
    hc = *(const bf16x8*)&Hs[i * HS_LD + q * 8];
#pragma unroll
    for (int ct = 0; ct < 2; ct++)
        bc[ct] = *(const bf16x8*)&W2T[(w * 32 + ct * 16 + i) * HD2 + q * 8];

#pragma unroll
    for (int ks = 0; ks < 8; ks++) {
        bf16x8 hn, bn2[2];
        if (ks < 7) {
            hn = *(const bf16x8*)&Hs[i * HS_LD + (ks + 1) * 32 + q * 8];
#pragma unroll
            for (int ct = 0; ct < 2; ct++)
                bn2[ct] =
                    *(const bf16x8*)&W2T[(w * 32 + ct * 16 + i) * HD2 + (ks + 1) * 32 + q * 8];
        }
#pragma unroll
        for (int ct = 0; ct < 2; ct++)
            acc2[ct] = __builtin_amdgcn_mfma_f32_16x16x32_bf16(hc, bc[ct], acc2[ct], 0, 0, 0);
        if (ks < 7) {
            hc = hn;
#pragma unroll
            for (int ct = 0; ct < 2; ct++) bc[ct] = bn2[ct];
        }
    }

    // ---- conv-out (+b2) -> bf16 LDS tile Ht (C-layout scatter; LDS absorbs it) ----
#pragma unroll
    for (int ct = 0; ct < 2; ct++) {
        float bb = b2l[w * 32 + ct * 16 + i];
#pragma unroll
        for (int r = 0; r < 4; r++)
            Ht[(q * 4 + r) * HT_LD + w * 32 + ct * 16 + i] = f2b(acc2[ct][r] + bb);
    }
    __syncthreads();

    // ---- row-wise COALESCED epilogue: residual add, h store, LN(128), zb store ----
    {
        const unsigned int* Ht32 = (const unsigned int*)Ht;
        unsigned int* h32 = (unsigned int*)h;
        unsigned int* zb32 = (unsigned int*)zb;
        float2 gg = *(const float2*)&gn[lane * 2];
        float2 cc = *(const float2*)&bn[lane * 2];
#pragma unroll
        for (int k = 0; k < 4; k++) {
            int rr = w * 4 + k;
            int row = nb + rr;
            unsigned int tv = Ht32[rr * (HT_LD / 2) + lane];
            float cx = b2f((unsigned short)tv), cy = b2f((unsigned short)(tv >> 16));
            if (add_residual) {
                unsigned int hv = h32[(size_t)row * 64 + lane];
                cx += b2f((unsigned short)hv);
                cy += b2f((unsigned short)(hv >> 16));
            }
            h32[(size_t)row * 64 + lane] = pack2(cx, cy);
            float s = cx + cy, sq = cx * cx + cy * cy;
#pragma unroll
            for (int m = 32; m >= 1; m >>= 1) {
                s += __shfl_xor(s, m);
                sq += __shfl_xor(sq, m);
            }
            float mu = s * (1.f / 128.f);
            float var = sq * (1.f / 128.f) - mu * mu;
            float inv = rsqrtf(var + LNEPS);
            float z0 = fmaxf(fmaf((cx - mu) * inv, gg.x, cc.x), 0.f);
            float z1 = fmaxf(fmaf((cy - mu) * inv, gg.y, cc.y), 0.f);
            zb32[(size_t)row * 64 + lane] = pack2(z0, z1);
        }
    }
}

// ---------------- atomic-free global mean pool (batch is sorted) ----------------
__global__ void k_pool(const unsigned short* __restrict__ zb, const int* __restrict__ gstart,
                       float* __restrict__ out) {
    int g = blockIdx.x;
    int c = threadIdx.x;  // 128
    int a = gstart[g], b = gstart[g + 1];
    float s0 = 0.f, s1 = 0.f;
    int n = a;
    for (; n + 2 <= b; n += 2) {
        s0 += b2f(zb[(size_t)n * HD + c]);
        s1 += b2f(zb[(size_t)(n + 1) * HD + c]);
    }
    if (n < b) s0 += b2f(zb[(size_t)n * HD + c]);
    out[g * HD + c] = (s0 + s1) / fmaxf((float)(b - a), 1.f);
}

// ---------------- launch ----------------
extern "C" void kernel_launch(void* const* d_in, const int* in_sizes, int n_in, void* d_out,
                              int out_size, void* d_ws, size_t ws_size, hipStream_t stream) {
    const float* x     = (const float*)d_in[0];
    const int* ei      = (const int*)d_in[1];
    const float* eattr = (const float*)d_in[2];
    const int* batch   = (const int*)d_in[3];
    const float* encW  = (const float*)d_in[4];
    const float* encB  = (const float*)d_in[5];
    const float* eW    = (const float*)d_in[6];
    const float* eB    = (const float*)d_in[7];
    const float* ln_g  = (const float*)d_in[8];
    const float* ln_b  = (const float*)d_in[9];
    const float* W1    = (const float*)d_in[10];
    const float* b1    = (const float*)d_in[11];
    const float* mlg   = (const float*)d_in[12];
    const float* mlb   = (const float*)d_in[13];
    const float* W2    = (const float*)d_in[14];
    const float* b2    = (const float*)d_in[15];
    const float* t     = (const float*)d_in[16];
    const int* src = ei;
    const int* dst = ei + NE;

    char* w = (char*)d_ws;
    auto alloc = [&](size_t bytes) {
        char* p = w;
        w += (bytes + 255) & ~size_t(255);
        return p;
    };
    unsigned short* h    = (unsigned short*)alloc(sizeof(unsigned short) * NN * HD);
    unsigned short* zb   = (unsigned short*)alloc(sizeof(unsigned short) * NN * HD);
    unsigned int* outb   = (unsigned int*)alloc(sizeof(unsigned int) * NN * HD / 2);
    float4* aperm        = (float4*)alloc(sizeof(float4) * NE);
    int* row_start       = (int*)alloc(sizeof(int) * (NN + 1));
    int* counts          = (int*)alloc(sizeof(int) * NN);
    int* cursor          = (int*)alloc(sizeof(int) * NN);
    int* incl            = (int*)alloc(sizeof(int) * NN);
    int* bsum            = (int*)alloc(sizeof(int) * 128);
    int* boff            = (int*)alloc(sizeof(int) * 128);
    int* gstart          = (int*)alloc(sizeof(int) * (NG + 1));
    unsigned short* W1T  = (unsigned short*)alloc(sizeof(unsigned short) * NL * HD * HD2);
    unsigned short* W2T  = (unsigned short*)alloc(sizeof(unsigned short) * NL * HD2 * HD);

    hipMemsetAsync(counts, 0, sizeof(int) * NN, stream);
    hipMemsetAsync(cursor, 0, sizeof(int) * NN, stream);

    k_setup<<<PREP_BLKS + ENC_BLKS + HIST_BLKS, 256, 0, stream>>>(x, encW, encB, zb, W1, W2,
                                                                  W1T, W2T, dst, counts);
    k_scan1<<<NSB, SCAN_B, 0, stream>>>(counts, incl, bsum);
    k_scan2<<<1, 128, 0, stream>>>(bsum, boff, NSB);
    k_scan3g<<<NSB + 2, SCAN_B, 0, stream>>>(incl, boff, row_start, batch, gstart);
    k_scatter<<<(NE + 255) / 256, 256, 0, stream>>>(src, dst, eattr, row_start, cursor, aperm);

    for (int l = 0; l < NL; l++) {
        k_aggregate<<<(NN + 3) / 4, 256, 0, stream>>>(zb, aperm, row_start, eW, eB, t, l, outb);
        int ln_next = (l + 1) % NL;  // layer 3 fuses the final ln (reuses layer-0 params)
        k_mlp<<<NN / BM, 256, 0, stream>>>(
            (const unsigned short*)outb, W1T + (size_t)l * HD * HD2, b1 + l * HD2,
            mlg + l * HD2, mlb + l * HD2, W2T + (size_t)l * HD2 * HD, b2 + l * HD, h,
            ln_g + ln_next * HD, ln_b + ln_next * HD, zb, l > 0);
    }
    k_pool<<<NG, HD, 0, stream>>>(zb, gstart, (float*)d_out);
}

// Round 14
// 543.167 us; speedup vs baseline: 1.0226x; 1.0226x over previous
//
#include <hip/hip_runtime.h>

#define NN 50000
#define NE 500000
#define HD 128
#define HD2 256
#define NL 4
#define NG 1000

constexpr float MSG_EPS = 1e-7f;
constexpr float LNEPS   = 1e-5f;
constexpr float LOG2E   = 1.4426950408889634f;

typedef float  f32x4  __attribute__((ext_vector_type(4)));
typedef float  f32x2  __attribute__((ext_vector_type(2)));
typedef __bf16 bf16x8 __attribute__((ext_vector_type(8)));

__device__ __forceinline__ unsigned short f2b(float f) {
    unsigned int u = __float_as_uint(f);
    unsigned int r = u + 0x7FFFu + ((u >> 16) & 1u);
    return (unsigned short)(r >> 16);
}
__device__ __forceinline__ float b2f(unsigned short h) {
    return __uint_as_float(((unsigned int)h) << 16);
}
__device__ __forceinline__ unsigned int pack2(float a, float b) {
    return (unsigned int)f2b(a) | ((unsigned int)f2b(b) << 16);
}

// ---------------- merged setup: weight prep + node encoder + dst histogram ----------
#define PREP_BLKS 512
#define ENC_BLKS 25000  // 2 nodes per 256-thr block
#define HIST_BLKS ((NE + 255) / 256)

__global__ void k_setup(const float* __restrict__ x, const float* __restrict__ encW,
                        const float* __restrict__ encB, unsigned short* __restrict__ zb,
                        const float* __restrict__ W1, const float* __restrict__ W2,
                        unsigned short* __restrict__ W1T, unsigned short* __restrict__ W2T,
                        const int* __restrict__ dst, int* __restrict__ counts) {
    int bid = blockIdx.x, tid = threadIdx.x;
    if (bid < PREP_BLKS) {
        int idx = bid * 256 + tid;  // 131072 total
        {
            int k = idx & 127, n = (idx >> 7) & 255, l = idx >> 15;
            W1T[idx] = f2b(W1[(l * 128 + k) * 256 + n]);
        }
        {
            int k = idx & 255, n = (idx >> 8) & 127, l = idx >> 15;
            W2T[idx] = f2b(W2[(l * 256 + k) * 128 + n]);
        }
    } else if (bid < PREP_BLKS + ENC_BLKS) {
        int n = (bid - PREP_BLKS) * 2 + (tid >> 7);
        int c = tid & 127;
        float xr[9];
#pragma unroll
        for (int k = 0; k < 9; k++) xr[k] = x[n * 9 + k];
        float acc = encB[c];
#pragma unroll
        for (int k = 0; k < 9; k++) acc = fmaf(xr[k], encW[k * HD + c], acc);
        zb[(size_t)n * HD + c] = f2b(acc);
    } else {
        int e = (bid - PREP_BLKS - ENC_BLKS) * 256 + tid;
        if (e < NE) atomicAdd(&counts[dst[e]], 1);
    }
}

// ---------------- CSR scan ----------------
#define SCAN_B 512
#define NSB ((NN + SCAN_B - 1) / SCAN_B)  // 98

__global__ void k_scan1(const int* __restrict__ counts, int* __restrict__ incl,
                        int* __restrict__ bsum) {
    __shared__ int s[SCAN_B];
    int i = blockIdx.x * SCAN_B + threadIdx.x;
    int v = (i < NN) ? counts[i] : 0;
    s[threadIdx.x] = v;
    __syncthreads();
    for (int off = 1; off < SCAN_B; off <<= 1) {
        int t = (threadIdx.x >= off) ? s[threadIdx.x - off] : 0;
        __syncthreads();
        s[threadIdx.x] += t;
        __syncthreads();
    }
    if (i < NN) incl[i] = s[threadIdx.x];
    if (threadIdx.x == SCAN_B - 1) bsum[blockIdx.x] = s[threadIdx.x];
}

__global__ void k_scan2(const int* __restrict__ bsum, int* __restrict__ boff, int nb) {
    __shared__ int s[128];
    int v = (threadIdx.x < nb) ? bsum[threadIdx.x] : 0;
    s[threadIdx.x] = v;
    __syncthreads();
    for (int off = 1; off < 128; off <<= 1) {
        int t = (threadIdx.x >= off) ? s[threadIdx.x - off] : 0;
        __syncthreads();
        s[threadIdx.x] += t;
        __syncthreads();
    }
    if (threadIdx.x < nb) boff[threadIdx.x] = s[threadIdx.x] - v;  // exclusive
}

// scan finalize + group-bounds binary search (merged)
__global__ void k_scan3g(const int* __restrict__ incl, const int* __restrict__ boff,
                         int* __restrict__ row_start, const int* __restrict__ batch,
                         int* __restrict__ gstart) {
    if (blockIdx.x < NSB) {
        int i = blockIdx.x * SCAN_B + threadIdx.x;
        if (i < NN) row_start[i + 1] = incl[i] + boff[blockIdx.x];
        if (i == 0) row_start[0] = 0;
    } else {
        int g = (blockIdx.x - NSB) * SCAN_B + threadIdx.x;
        if (g > NG) return;
        int lo = 0, hi = NN;
        while (lo < hi) {
            int mid = (lo + hi) >> 1;
            if (batch[mid] < g) lo = mid + 1;
            else hi = mid;
        }
        gstart[g] = lo;
    }
}

// pack {attr0, attr1, attr2, src} per CSR slot
__global__ void k_scatter(const int* __restrict__ src, const int* __restrict__ dst,
                          const float* __restrict__ eattr, const int* __restrict__ row_start,
                          int* __restrict__ cursor, float4* __restrict__ aperm) {
    int e = blockIdx.x * blockDim.x + threadIdx.x;
    if (e >= NE) return;
    int d = dst[e];
    int p = row_start[d] + atomicAdd(&cursor[d], 1);
    float4 v;
    v.x = eattr[e * 3 + 0];
    v.y = eattr[e * 3 + 1];
    v.z = eattr[e * 3 + 2];
    v.w = __int_as_float(src[e]);
    aperm[p] = v;
}

// ---------------- per-edge softmax-agg accumulate (2 ch/lane, packed fp32) ----------
__device__ __forceinline__ void edge_acc2(float4 a, unsigned int zz, f32x2 w0, f32x2 w1,
                                          f32x2 w2, f32x2 bb, float t2, f32x2& num,
                                          f32x2& wm) {
    f32x2 z;
    z.x = __uint_as_float(zz << 16);
    z.y = __uint_as_float(zz & 0xFFFF0000u);
    f32x2 m = z + bb + a.x * w0 + a.y * w1 + a.z * w2;  // v_pk_fma chain
    m.x = fmaxf(m.x, 0.f);
    m.y = fmaxf(m.y, 0.f);
    f32x2 e;
    e.x = exp2f(t2 * m.x);
    e.y = exp2f(t2 * m.y);
    num += e;     // v_pk_add
    wm += m * e;  // v_pk_fma
}

// ---------------- softmax aggregation: one wave per node, 2 ch/lane, unroll-8 ------
__global__ __launch_bounds__(256) void k_aggregate(const unsigned short* __restrict__ zbin,
                                                   const float4* __restrict__ aperm,
                                                   const int* __restrict__ row_start,
                                                   const float* __restrict__ We,
                                                   const float* __restrict__ be,
                                                   const float* __restrict__ t, int layer,
                                                   unsigned int* __restrict__ outb) {
    int w = threadIdx.x >> 6, lane = threadIdx.x & 63;
    int n = blockIdx.x * 4 + w;
    if (n >= NN) return;
    int c = lane * 2;
    f32x2 w0 = *(const f32x2*)&We[c];
    f32x2 w1 = *(const f32x2*)&We[HD + c];
    f32x2 w2 = *(const f32x2*)&We[2 * HD + c];
    f32x2 bb = *(const f32x2*)&be[c];
    float t2 = t[layer] * LOG2E;
    int s0 = __builtin_amdgcn_readfirstlane(row_start[n]);
    int s1 = __builtin_amdgcn_readfirstlane(row_start[n + 1]);
    f32x2 num = (f32x2){0.f, 0.f}, wm = (f32x2){0.f, 0.f};
    const unsigned int* z32 = (const unsigned int*)zbin;
    int p = s0;
    for (; p + 8 <= s1; p += 8) {
        float4 A[8];
#pragma unroll
        for (int j = 0; j < 8; j++) A[j] = aperm[p + j];
        unsigned int Z[8];
#pragma unroll
        for (int j = 0; j < 8; j++) {
            int sj = __builtin_amdgcn_readfirstlane(__float_as_int(A[j].w));
            Z[j] = z32[(size_t)sj * 64 + lane];
        }
#pragma unroll
        for (int j = 0; j < 8; j++) edge_acc2(A[j], Z[j], w0, w1, w2, bb, t2, num, wm);
    }
    for (; p + 4 <= s1; p += 4) {
        float4 A[4];
#pragma unroll
        for (int j = 0; j < 4; j++) A[j] = aperm[p + j];
        unsigned int Z[4];
#pragma unroll
        for (int j = 0; j < 4; j++) {
            int sj = __builtin_amdgcn_readfirstlane(__float_as_int(A[j].w));
            Z[j] = z32[(size_t)sj * 64 + lane];
        }
#pragma unroll
        for (int j = 0; j < 4; j++) edge_acc2(A[j], Z[j], w0, w1, w2, bb, t2, num, wm);
    }
    for (; p < s1; p++) {
        float4 a = aperm[p];
        int sj = __builtin_amdgcn_readfirstlane(__float_as_int(a.w));
        unsigned int zz = z32[(size_t)sj * 64 + lane];
        edge_acc2(a, zz, w0, w1, w2, bb, t2, num, wm);
    }
    unsigned int zn = z32[(size_t)n * 64 + lane];
    bool has = s1 > s0;
    float ox = (has ? (wm.x / num.x + MSG_EPS) : 0.f) + __uint_as_float(zn << 16);
    float oy = (has ? (wm.y / num.y + MSG_EPS) : 0.f) + __uint_as_float(zn & 0xFFFF0000u);
    outb[(size_t)n * 64 + lane] = pack2(ox, oy);
}

// ---------------- fused MFMA MLP + next-layer LN+relu, BM=64 x 512 threads ----------
// 8 waves; wave w owns GEMM1 cols w*32..+31 (2 ct) and GEMM2 cols w*16..+15 (1 ct)
// over all 64 rows (4 rt). Per-block weight stream = 128 KB amortized over 64 nodes
// (half of BM=32). Ht ALIASES Hs (all waves done reading Hs after GEMM2; +1 barrier).
// LDS = 64*264*2 + 4K stats = ~38.7 KB -> 4 blocks/CU.
#define BM 64
#define HS_LD 264  // bf16 row stride (256+8)
#define HT_LD 136  // bf16 row stride (128+8); as uint: 68

__global__ __launch_bounds__(512) void k_mlp(const unsigned short* __restrict__ outb,
                                             const unsigned short* __restrict__ W1T,
                                             const float* __restrict__ b1l,
                                             const float* __restrict__ lgl,
                                             const float* __restrict__ lbl,
                                             const unsigned short* __restrict__ W2T,
                                             const float* __restrict__ b2l,
                                             unsigned short* __restrict__ h,
                                             const float* __restrict__ gn,
                                             const float* __restrict__ bn,
                                             unsigned short* __restrict__ zb,
                                             int add_residual) {
    __shared__ __align__(16) unsigned short Hs[BM * HS_LD];  // 33792 B (Ht aliases this)
    __shared__ __align__(16) float2 st1[4][16][8];           // 4096 B

    int nb = blockIdx.x * BM;
    int tid = threadIdx.x;
    int w = tid >> 6, lane = tid & 63, q = lane >> 4, i = lane & 15;

    // ---- GEMM1: 64x256, K=128; A from global bf16 (L1-shared across waves),
    //      B (weights) register-lookahead ----
    f32x4 acc[4][2];
#pragma unroll
    for (int rt = 0; rt < 4; rt++)
#pragma unroll
        for (int ct = 0; ct < 2; ct++) acc[rt][ct] = (f32x4){0.f, 0.f, 0.f, 0.f};

    bf16x8 bcur[2];
#pragma unroll
    for (int ct = 0; ct < 2; ct++)
        bcur[ct] = *(const bf16x8*)&W1T[(w * 32 + ct * 16 + i) * HD + q * 8];

#pragma unroll
    for (int ks = 0; ks < 4; ks++) {
        bf16x8 bnxt[2];
        if (ks < 3) {
#pragma unroll
            for (int ct = 0; ct < 2; ct++)
                bnxt[ct] =
                    *(const bf16x8*)&W1T[(w * 32 + ct * 16 + i) * HD + (ks + 1) * 32 + q * 8];
        }
#pragma unroll
        for (int rt = 0; rt < 4; rt++) {
            int row = nb + rt * 16 + i;
            bf16x8 a = (row < NN) ? *(const bf16x8*)&outb[(size_t)row * HD + ks * 32 + q * 8]
                                  : (bf16x8)(__bf16)0.f;
#pragma unroll
            for (int ct = 0; ct < 2; ct++)
                acc[rt][ct] =
                    __builtin_amdgcn_mfma_f32_16x16x32_bf16(a, bcur[ct], acc[rt][ct], 0, 0, 0);
        }
        if (ks < 3) {
#pragma unroll
            for (int ct = 0; ct < 2; ct++) bcur[ct] = bnxt[ct];
        }
    }

    // ---- +b1 ----
#pragma unroll
    for (int ct = 0; ct < 2; ct++) {
        float bb = b1l[w * 32 + ct * 16 + i];
#pragma unroll
        for (int rt = 0; rt < 4; rt++)
#pragma unroll
            for (int r = 0; r < 4; r++) acc[rt][ct][r] += bb;
    }

    // ---- LN(256) stats: per-wave partial (2 ct) -> shuffle over 16 lanes -> st1 ----
    {
        float sv[4][4], qv[4][4];
#pragma unroll
        for (int rt = 0; rt < 4; rt++)
#pragma unroll
            for (int r = 0; r < 4; r++) {
                sv[rt][r] = acc[rt][0][r] + acc[rt][1][r];
                qv[rt][r] = fmaf(acc[rt][0][r], acc[rt][0][r],
                                 acc[rt][1][r] * acc[rt][1][r]);
            }
#pragma unroll
        for (int m = 1; m <= 8; m <<= 1)
#pragma unroll
            for (int rt = 0; rt < 4; rt++)
#pragma unroll
                for (int r = 0; r < 4; r++) {
                    sv[rt][r] += __shfl_xor(sv[rt][r], m);
                    qv[rt][r] += __shfl_xor(qv[rt][r], m);
                }
        if (i == 0) {
#pragma unroll
            for (int rt = 0; rt < 4; rt++)
#pragma unroll
                for (int r = 0; r < 4; r++)
                    st1[rt][q * 4 + r][w] = make_float2(sv[rt][r], qv[rt][r]);
        }
    }
    __syncthreads();

    // ---- finalize stats (sum 8 wave-partials), apply LN+relu, pack bf16 -> Hs ----
    {
        float mu[4][4], inv[4][4];
#pragma unroll
        for (int rt = 0; rt < 4; rt++)
#pragma unroll
            for (int r = 0; r < 4; r++) {
                const float4* sp = (const float4*)&st1[rt][q * 4 + r][0];
                float4 a = sp[0], b = sp[1], cc4 = sp[2], d4 = sp[3];
                float S = a.x + a.z + b.x + b.z + cc4.x + cc4.z + d4.x + d4.z;
                float Q = a.y + a.w + b.y + b.w + cc4.y + cc4.w + d4.y + d4.w;
                float m_ = S * (1.f / 256.f);
                float v_ = Q * (1.f / 256.f) - m_ * m_;
                mu[rt][r] = m_;
                inv[rt][r] = rsqrtf(v_ + LNEPS);
            }
#pragma unroll
        for (int ct = 0; ct < 2; ct++) {
            float g = lgl[w * 32 + ct * 16 + i];
            float c = lbl[w * 32 + ct * 16 + i];
#pragma unroll
            for (int rt = 0; rt < 4; rt++)
#pragma unroll
                for (int r = 0; r < 4; r++) {
                    float v =
                        fmaxf(fmaf((acc[rt][ct][r] - mu[rt][r]) * inv[rt][r], g, c), 0.f);
                    Hs[(rt * 16 + q * 4 + r) * HS_LD + w * 32 + ct * 16 + i] = f2b(v);
                }
        }
    }
    __syncthreads();

    // ---- GEMM2: 64x128, K=256; A from Hs, B register-lookahead ----
    f32x4 acc2[4];
#pragma unroll
    for (int rt = 0; rt < 4; rt++) acc2[rt] = (f32x4){0.f, 0.f, 0.f, 0.f};

    bf16x8 bc = *(const bf16x8*)&W2T[(w * 16 + i) * HD2 + q * 8];
#pragma unroll
    for (int ks = 0; ks < 8; ks++) {
        bf16x8 bn2;
        if (ks < 7) bn2 = *(const bf16x8*)&W2T[(w * 16 + i) * HD2 + (ks + 1) * 32 + q * 8];
#pragma unroll
        for (int rt = 0; rt < 4; rt++) {
            bf16x8 a = *(const bf16x8*)&Hs[(rt * 16 + i) * HS_LD + ks * 32 + q * 8];
            acc2[rt] = __builtin_amdgcn_mfma_f32_16x16x32_bf16(a, bc, acc2[rt], 0, 0, 0);
        }
        if (ks < 7) bc = bn2;
    }
    __syncthreads();  // all waves done reading Hs -> safe to overwrite (Ht aliases Hs)

    // ---- conv-out (+b2) -> bf16 tile Ht (aliased into Hs) ----
    unsigned short* Ht = Hs;
    {
        float bb = b2l[w * 16 + i];
#pragma unroll
        for (int rt = 0; rt < 4; rt++)
#pragma unroll
            for (int r = 0; r < 4; r++)
                Ht[(rt * 16 + q * 4 + r) * HT_LD + w * 16 + i] = f2b(acc2[rt][r] + bb);
    }
    __syncthreads();

    // ---- row-wise COALESCED epilogue: residual add, h store, LN(128), zb store ----
    {
        const unsigned int* Ht32 = (const unsigned int*)Ht;
        unsigned int* h32 = (unsigned int*)h;
        unsigned int* zb32 = (unsigned int*)zb;
        float2 gg = *(const float2*)&gn[lane * 2];
        float2 cc = *(const float2*)&bn[lane * 2];
#pragma unroll
        for (int k = 0; k < 8; k++) {
            int rr = w * 8 + k;
            int row = nb + rr;
            if (row >= NN) break;
            unsigned int tv = Ht32[rr * (HT_LD / 2) + lane];
            float cx = b2f((unsigned short)tv), cy = b2f((unsigned short)(tv >> 16));
            if (add_residual) {
                unsigned int hv = h32[(size_t)row * 64 + lane];
                cx += b2f((unsigned short)hv);
                cy += b2f((unsigned short)(hv >> 16));
            }
            h32[(size_t)row * 64 + lane] = pack2(cx, cy);
            float s = cx + cy, sq = cx * cx + cy * cy;
#pragma unroll
            for (int m = 32; m >= 1; m >>= 1) {
                s += __shfl_xor(s, m);
                sq += __shfl_xor(sq, m);
            }
            float mu = s * (1.f / 128.f);
            float var = sq * (1.f / 128.f) - mu * mu;
            float inv = rsqrtf(var + LNEPS);
            float z0 = fmaxf(fmaf((cx - mu) * inv, gg.x, cc.x), 0.f);
            float z1 = fmaxf(fmaf((cy - mu) * inv, gg.y, cc.y), 0.f);
            zb32[(size_t)row * 64 + lane] = pack2(z0, z1);
        }
    }
}

// ---------------- atomic-free global mean pool (batch is sorted) ----------------
__global__ void k_pool(const unsigned short* __restrict__ zb, const int* __restrict__ gstart,
                       float* __restrict__ out) {
    int g = blockIdx.x;
    int c = threadIdx.x;  // 128
    int a = gstart[g], b = gstart[g + 1];
    float s0 = 0.f, s1 = 0.f;
    int n = a;
    for (; n + 2 <= b; n += 2) {
        s0 += b2f(zb[(size_t)n * HD + c]);
        s1 += b2f(zb[(size_t)(n + 1) * HD + c]);
    }
    if (n < b) s0 += b2f(zb[(size_t)n * HD + c]);
    out[g * HD + c] = (s0 + s1) / fmaxf((float)(b - a), 1.f);
}

// ---------------- launch ----------------
extern "C" void kernel_launch(void* const* d_in, const int* in_sizes, int n_in, void* d_out,
                              int out_size, void* d_ws, size_t ws_size, hipStream_t stream) {
    const float* x     = (const float*)d_in[0];
    const int* ei      = (const int*)d_in[1];
    const float* eattr = (const float*)d_in[2];
    const int* batch   = (const int*)d_in[3];
    const float* encW  = (const float*)d_in[4];
    const float* encB  = (const float*)d_in[5];
    const float* eW    = (const float*)d_in[6];
    const float* eB    = (const float*)d_in[7];
    const float* ln_g  = (const float*)d_in[8];
    const float* ln_b  = (const float*)d_in[9];
    const float* W1    = (const float*)d_in[10];
    const float* b1    = (const float*)d_in[11];
    const float* mlg   = (const float*)d_in[12];
    const float* mlb   = (const float*)d_in[13];
    const float* W2    = (const float*)d_in[14];
    const float* b2    = (const float*)d_in[15];
    const float* t     = (const float*)d_in[16];
    const int* src = ei;
    const int* dst = ei + NE;

    char* w = (char*)d_ws;
    auto alloc = [&](size_t bytes) {
        char* p = w;
        w += (bytes + 255) & ~size_t(255);
        return p;
    };
    unsigned short* h    = (unsigned short*)alloc(sizeof(unsigned short) * NN * HD);
    unsigned short* zb   = (unsigned short*)alloc(sizeof(unsigned short) * NN * HD);
    unsigned int* outb   = (unsigned int*)alloc(sizeof(unsigned int) * NN * HD / 2);
    float4* aperm        = (float4*)alloc(sizeof(float4) * NE);
    int* row_start       = (int*)alloc(sizeof(int) * (NN + 1));
    int* counts          = (int*)alloc(sizeof(int) * NN);
    int* cursor          = (int*)alloc(sizeof(int) * NN);
    int* incl            = (int*)alloc(sizeof(int) * NN);
    int* bsum            = (int*)alloc(sizeof(int) * 128);
    int* boff            = (int*)alloc(sizeof(int) * 128);
    int* gstart          = (int*)alloc(sizeof(int) * (NG + 1));
    unsigned short* W1T  = (unsigned short*)alloc(sizeof(unsigned short) * NL * HD * HD2);
    unsigned short* W2T  = (unsigned short*)alloc(sizeof(unsigned short) * NL * HD2 * HD);

    hipMemsetAsync(counts, 0, sizeof(int) * NN, stream);
    hipMemsetAsync(cursor, 0, sizeof(int) * NN, stream);

    k_setup<<<PREP_BLKS + ENC_BLKS + HIST_BLKS, 256, 0, stream>>>(x, encW, encB, zb, W1, W2,
                                                                  W1T, W2T, dst, counts);
    k_scan1<<<NSB, SCAN_B, 0, stream>>>(counts, incl, bsum);
    k_scan2<<<1, 128, 0, stream>>>(bsum, boff, NSB);
    k_scan3g<<<NSB + 2, SCAN_B, 0, stream>>>(incl, boff, row_start, batch, gstart);
    k_scatter<<<(NE + 255) / 256, 256, 0, stream>>>(src, dst, eattr, row_start, cursor, aperm);

    for (int l = 0; l < NL; l++) {
        k_aggregate<<<(NN + 3) / 4, 256, 0, stream>>>(zb, aperm, row_start, eW, eB, t, l, outb);
        int ln_next = (l + 1) % NL;  // layer 3 fuses the final ln (reuses layer-0 params)
        k_mlp<<<(NN + BM - 1) / BM, 512, 0, stream>>>(
            (const unsigned short*)outb, W1T + (size_t)l * HD * HD2, b1 + l * HD2,
            mlg + l * HD2, mlb + l * HD2, W2T + (size_t)l * HD2 * HD, b2 + l * HD, h,
            ln_g + ln_next * HD, ln_b + ln_next * HD, zb, l > 0);
    }
    k_pool<<<NG, HD, 0, stream>>>(zb, gstart, (float*)d_out);
}